// Round 4
// baseline (639.312 us; speedup 1.0000x reference)
//
#include <hip/hip_runtime.h>
#include <hip/hip_bf16.h>

// Problem constants
#define R_TOT   8192
#define A14     14
#define A_TOT   (R_TOT * A14)     // 114688
#define QR_ELEMS (R_TOT * 256)    // 2097152

typedef __attribute__((ext_vector_type(8))) short bf16x8;
typedef __attribute__((ext_vector_type(4))) float f32x4;
typedef __attribute__((ext_vector_type(4))) short short4v;

#define MFMA16(a, b, c) __builtin_amdgcn_mfma_f32_16x16x32_bf16((a), (b), (c), 0, 0, 0)

// ---------------------------------------------------------------------------
// Weight transpose + bf16 cast:  w[K][N] fp32  ->  wT[N][K] bf16
// ---------------------------------------------------------------------------
__global__ __launch_bounds__(256) void wtrans_kernel(
    const float* __restrict__ w, __hip_bfloat16* __restrict__ wT, int K, int N)
{
    __shared__ float tile[32][33];
    const int kb = blockIdx.x * 32, nb = blockIdx.y * 32;
    const int tx = threadIdx.x & 31, ty = threadIdx.x >> 5;   // 32 x 8
    #pragma unroll
    for (int i = 0; i < 32; i += 8) {
        int k = kb + ty + i, n = nb + tx;
        tile[ty + i][tx] = (k < K && n < N) ? w[(size_t)k * N + n] : 0.f;
    }
    __syncthreads();
    #pragma unroll
    for (int i = 0; i < 32; i += 8) {
        int n = nb + ty + i, k = kb + tx;
        if (n < N && k < K) wT[(size_t)n * K + k] = __float2bfloat16(tile[tx][ty + i]);
    }
}

// ---------------------------------------------------------------------------
// Fused sam MLP + masked softmax + pooling.
// Block = 4 residues = 56 atoms, padded to M=64. 512 threads = 8 waves
// (2 M-groups x 4 N-groups). z staged in K-chunks of 128.
//   L1: z[64x512] @ w1 -> h1[64x256]   (MFMA, leaky)
//   L2: h1 @ w2 -> h2 (stored back into h1 buffer)   (MFMA, leaky)
//   L3: h2 @ w3 -> sa[64x16]           (MFMA)
//   softmax over 14 atoms per residue/channel, then pooled qh/ph (bf16 out).
// LDS: zc 17,408 B (aliased by sa+aw after L1) + h1 33,792 B = 51,200 B.
// ---------------------------------------------------------------------------
__global__ __launch_bounds__(512, 4) void sampool_kernel(
    const float* __restrict__ q, const float* __restrict__ p,
    const float* __restrict__ atom_mask,
    const __hip_bfloat16* __restrict__ wT1, const float* __restrict__ b1,
    const __hip_bfloat16* __restrict__ wT2, const float* __restrict__ b2,
    const __hip_bfloat16* __restrict__ wT3, const float* __restrict__ b3,
    __hip_bfloat16* __restrict__ qh, __hip_bfloat16* __restrict__ ph)
{
    __shared__ __align__(16) char smemA[64 * 136 * 2];   // 17,408 B
    __shared__ __align__(16) char smemB[64 * 264 * 2];   // 33,792 B

    __hip_bfloat16 (* const zc)[136]  = (__hip_bfloat16(*)[136])smemA;
    __hip_bfloat16 (* const h1l)[264] = (__hip_bfloat16(*)[264])smemB;
    float (* const sa_lds)[16] = (float(*)[16])smemA;              // 4,096 B
    float* const aw_base = (float*)(smemA + 4096);                 // 2x[4][14][8] = 3,584 B

    const int tid = threadIdx.x;
    const int r0  = blockIdx.x * 4;      // 4 residues per block
    const int a0  = r0 * A14;            // first atom row (56 real rows, pad to 64)
    const int wv  = tid >> 6;
    const int l   = tid & 63;
    const int lr  = l & 15;
    const int lh  = l >> 4;
    const int mbase = (wv >> 2) * 32;
    const int nbase = (wv & 3) * 64;

    // ---- Layer 1: K=512 in 4 chunks of 128 ----
    {
        f32x4 acc[2][4] = {};
        for (int chunk = 0; chunk < 4; ++chunk) {
            // stage zc[64][128]: 64 rows x 128 cols = 8192 elems, 4 per thread-iter
            #pragma unroll
            for (int it = 0; it < 4; ++it) {
                const int g  = tid + it * 512;       // 0..2047
                const int m  = g >> 5;               // 0..63
                const int c4 = (g & 31) * 4;         // 0..124
                const int ar = a0 + m;
                const size_t arow = (size_t)((ar < A_TOT) ? ar : (A_TOT - 1));
                __hip_bfloat16 t[4];
                if (chunk < 2) {
                    const float4 v = *(const float4*)&q[arow * 256 + chunk * 128 + c4];
                    t[0] = __float2bfloat16(v.x); t[1] = __float2bfloat16(v.y);
                    t[2] = __float2bfloat16(v.z); t[3] = __float2bfloat16(v.w);
                } else {
                    const int cc = (chunk - 2) * 128 + c4;
                    const float4 pa = *(const float4*)&p[arow * 768 + 0 * 256 + cc];
                    const float4 pb = *(const float4*)&p[arow * 768 + 1 * 256 + cc];
                    const float4 pc = *(const float4*)&p[arow * 768 + 2 * 256 + cc];
                    t[0] = __float2bfloat16(sqrtf(pa.x*pa.x + pb.x*pb.x + pc.x*pc.x + 1e-6f));
                    t[1] = __float2bfloat16(sqrtf(pa.y*pa.y + pb.y*pb.y + pc.y*pc.y + 1e-6f));
                    t[2] = __float2bfloat16(sqrtf(pa.z*pa.z + pb.z*pb.z + pc.z*pc.z + 1e-6f));
                    t[3] = __float2bfloat16(sqrtf(pa.w*pa.w + pb.w*pb.w + pc.w*pc.w + 1e-6f));
                }
                *(short4v*)&zc[m][c4] = *(const short4v*)t;
            }
            __syncthreads();
            #pragma unroll
            for (int k0 = 0; k0 < 128; k0 += 32) {
                const int kc = k0 + lh * 8;
                const bf16x8 af0 = *(const bf16x8*)&zc[mbase + lr][kc];
                const bf16x8 af1 = *(const bf16x8*)&zc[mbase + 16 + lr][kc];
                bf16x8 bfv[4];
                #pragma unroll
                for (int nt = 0; nt < 4; ++nt)
                    bfv[nt] = *(const bf16x8*)&wT1[(size_t)(nbase + nt*16 + lr) * 512 + chunk * 128 + kc];
                #pragma unroll
                for (int nt = 0; nt < 4; ++nt) {
                    acc[0][nt] = MFMA16(af0, bfv[nt], acc[0][nt]);
                    acc[1][nt] = MFMA16(af1, bfv[nt], acc[1][nt]);
                }
            }
            __syncthreads();
        }
        // bias + leaky -> h1 (LDS)
        #pragma unroll
        for (int nt = 0; nt < 4; ++nt) {
            const int n = nbase + nt * 16 + lr;
            const float bv = b1[n];
            #pragma unroll
            for (int mt = 0; mt < 2; ++mt)
                #pragma unroll
                for (int v = 0; v < 4; ++v) {
                    float x = acc[mt][nt][v] + bv;
                    x = x >= 0.f ? x : 0.01f * x;
                    h1l[mbase + mt * 16 + lh * 4 + v][n] = __float2bfloat16(x);
                }
        }
    }
    __syncthreads();

    // ---- Layer 2: K=256 ----
    {
        f32x4 acc[2][4] = {};
        #pragma unroll 2
        for (int k0 = 0; k0 < 256; k0 += 32) {
            const int kc = k0 + lh * 8;
            const bf16x8 af0 = *(const bf16x8*)&h1l[mbase + lr][kc];
            const bf16x8 af1 = *(const bf16x8*)&h1l[mbase + 16 + lr][kc];
            bf16x8 bfv[4];
            #pragma unroll
            for (int nt = 0; nt < 4; ++nt)
                bfv[nt] = *(const bf16x8*)&wT2[(size_t)(nbase + nt*16 + lr) * 256 + kc];
            #pragma unroll
            for (int nt = 0; nt < 4; ++nt) {
                acc[0][nt] = MFMA16(af0, bfv[nt], acc[0][nt]);
                acc[1][nt] = MFMA16(af1, bfv[nt], acc[1][nt]);
            }
        }
        __syncthreads();   // everyone done READING h1 before overwrite with h2
        #pragma unroll
        for (int nt = 0; nt < 4; ++nt) {
            const int n = nbase + nt * 16 + lr;
            const float bv = b2[n];
            #pragma unroll
            for (int mt = 0; mt < 2; ++mt)
                #pragma unroll
                for (int v = 0; v < 4; ++v) {
                    float x = acc[mt][nt][v] + bv;
                    x = x >= 0.f ? x : 0.01f * x;
                    h1l[mbase + mt * 16 + lh * 4 + v][n] = __float2bfloat16(x);  // h2
                }
        }
    }
    __syncthreads();

    // ---- Layer 3: K=256 -> 16 cols; waves 0..3 each own one 16-row frag ----
    if (wv < 4) {
        f32x4 a3 = {};
        #pragma unroll
        for (int k0 = 0; k0 < 256; k0 += 32) {
            const int kc = k0 + lh * 8;
            const bf16x8 af = *(const bf16x8*)&h1l[wv * 16 + lr][kc];
            const bf16x8 bw = *(const bf16x8*)&wT3[(size_t)lr * 256 + kc];
            a3 = MFMA16(af, bw, a3);
        }
        const float bv = b3[lr];
        #pragma unroll
        for (int v = 0; v < 4; ++v)
            sa_lds[wv * 16 + lh * 4 + v][lr] = a3[v] + bv;
    }
    __syncthreads();

    // ---- masked softmax over atoms: 4 residues x 16 channels = 64 threads ----
    if (tid < 64) {
        const int res = tid >> 4, ch = tid & 15;
        const size_t rg = (size_t)(r0 + res);
        float sl[14];
        float mx = -3.0e38f, anym = 0.f;
        #pragma unroll
        for (int a = 0; a < 14; ++a) {
            const float m = atom_mask[rg * 14 + a];
            anym = fmaxf(anym, m);
            const float lm = (1.0f - m + 1e-6f) / (m - 1e-6f);
            const float v = sa_lds[res * 14 + a][ch] + lm;
            sl[a] = v;
            mx = fmaxf(mx, v);
        }
        float s = 0.f;
        #pragma unroll
        for (int a = 0; a < 14; ++a) { sl[a] = expf(sl[a] - mx); s += sl[a]; }
        const float inv = ((anym != 0.f) ? 1.f : 0.f) / s;   // fold residue mask
        float* const aw = aw_base + ((ch & 1) ? 448 : 0);
        const int h = ch >> 1;
        #pragma unroll
        for (int a = 0; a < 14; ++a)
            aw[res * 112 + a * 8 + h] = sl[a] * inv;
    }
    __syncthreads();

    // ---- pooling: qh[r,c,h], ph[r,x,c,h]  (half the threads per residue-pair) ----
    {
        const int half = tid >> 8;          // 0..1 -> residues {0,1} / {2,3}
        const int c    = tid & 255;
        const float* const aw0 = aw_base;
        const float* const aw1 = aw_base + 448;
        for (int rr = 0; rr < 2; ++rr) {
            const int res = half * 2 + rr;
            const size_t rg = (size_t)(r0 + res);
            float acc8[8] = {0,0,0,0,0,0,0,0};
            #pragma unroll
            for (int a = 0; a < 14; ++a) {
                const float qv = q[(rg * 14 + a) * 256 + c];
                #pragma unroll
                for (int h = 0; h < 8; ++h)
                    acc8[h] = fmaf(qv, aw0[res * 112 + a * 8 + h], acc8[h]);
            }
            alignas(16) __hip_bfloat16 tmp[8];
            #pragma unroll
            for (int h = 0; h < 8; ++h) tmp[h] = __float2bfloat16(acc8[h]);
            *reinterpret_cast<int4*>(&qh[rg * 2048 + (size_t)c * 8]) =
                *reinterpret_cast<const int4*>(tmp);

            for (int x = 0; x < 3; ++x) {
                #pragma unroll
                for (int h = 0; h < 8; ++h) acc8[h] = 0.f;
                #pragma unroll
                for (int a = 0; a < 14; ++a) {
                    const float pv = p[(rg * 14 + a) * 768 + (size_t)x * 256 + c];
                    #pragma unroll
                    for (int h = 0; h < 8; ++h)
                        acc8[h] = fmaf(pv, aw1[res * 112 + a * 8 + h], acc8[h]);
                }
                #pragma unroll
                for (int h = 0; h < 8; ++h) tmp[h] = __float2bfloat16(acc8[h]);
                *reinterpret_cast<int4*>(&ph[(rg * 3 + x) * 2048 + (size_t)c * 8]) =
                    *reinterpret_cast<const int4*>(tmp);
            }
        }
    }
}

// ---------------------------------------------------------------------------
// Generic bf16-MFMA MLP layer: out[M,256] = act(x[M,K] @ w[K,256] (+bias))
// x bf16, wT bf16 [256][K]. 32 rows/block, 4 waves (64 cols each).
// ---------------------------------------------------------------------------
template <int K, bool BIAS, bool LEAKY, bool OUT_BF16>
__global__ __launch_bounds__(256) void mlp_mfma_kernel(
    const __hip_bfloat16* __restrict__ x, const __hip_bfloat16* __restrict__ wT,
    const float* __restrict__ bias, void* __restrict__ out)
{
    constexpr int KC = (K < 256) ? K : 256;
    __shared__ __hip_bfloat16 xlds[32][KC + 8];

    const int tid = threadIdx.x;
    const int a0  = blockIdx.x * 32;
    const int wv  = tid >> 6;
    const int l   = tid & 63;
    const int lr  = l & 15;
    const int lh  = l >> 4;
    const int nbase = wv * 64;

    f32x4 acc[2][4] = {};

    for (int chunk = 0; chunk < K; chunk += KC) {
        __syncthreads();
        for (int u = tid; u < 32 * (KC / 8); u += 256) {
            const int m  = u / (KC / 8);
            const int c8 = (u % (KC / 8)) * 8;
            const int4 v = *(const int4*)&x[(size_t)(a0 + m) * K + chunk + c8];
            *(int4*)&xlds[m][c8] = v;
        }
        __syncthreads();

        #pragma unroll 2
        for (int k0 = 0; k0 < KC; k0 += 32) {
            const int kc = k0 + lh * 8;
            const bf16x8 af0 = *(const bf16x8*)&xlds[lr][kc];
            const bf16x8 af1 = *(const bf16x8*)&xlds[16 + lr][kc];
            bf16x8 bfv[4];
            #pragma unroll
            for (int nt = 0; nt < 4; ++nt)
                bfv[nt] = *(const bf16x8*)&wT[(size_t)(nbase + nt * 16 + lr) * K + chunk + kc];
            #pragma unroll
            for (int nt = 0; nt < 4; ++nt) {
                acc[0][nt] = MFMA16(af0, bfv[nt], acc[0][nt]);
                acc[1][nt] = MFMA16(af1, bfv[nt], acc[1][nt]);
            }
        }
    }

    #pragma unroll
    for (int nt = 0; nt < 4; ++nt) {
        const int n = nbase + nt * 16 + lr;
        const float bv = BIAS ? bias[n] : 0.0f;
        #pragma unroll
        for (int mt = 0; mt < 2; ++mt)
            #pragma unroll
            for (int v = 0; v < 4; ++v) {
                float xv = acc[mt][nt][v] + bv;
                if (LEAKY) xv = xv >= 0.f ? xv : 0.01f * xv;
                const size_t oidx = (size_t)(a0 + mt * 16 + lh * 4 + v) * 256 + n;
                if (OUT_BF16) ((__hip_bfloat16*)out)[oidx] = __float2bfloat16(xv);
                else          ((float*)out)[oidx] = xv;
            }
    }
}

// ---------------------------------------------------------------------------
extern "C" void kernel_launch(void* const* d_in, const int* in_sizes, int n_in,
                              void* d_out, int out_size, void* d_ws, size_t ws_size,
                              hipStream_t stream)
{
    const float* q    = (const float*)d_in[0];
    const float* p    = (const float*)d_in[1];
    const float* amsk = (const float*)d_in[2];
    const float* sw1  = (const float*)d_in[3];
    const float* sb1  = (const float*)d_in[4];
    const float* sw2  = (const float*)d_in[5];
    const float* sb2  = (const float*)d_in[6];
    const float* sw3  = (const float*)d_in[7];
    const float* sb3  = (const float*)d_in[8];
    const float* zw1  = (const float*)d_in[9];
    const float* zb1  = (const float*)d_in[10];
    const float* zw2  = (const float*)d_in[11];
    const float* zb2  = (const float*)d_in[12];
    const float* zw3  = (const float*)d_in[13];
    const float* zb3  = (const float*)d_in[14];
    const float* zvw  = (const float*)d_in[15];

    // workspace carve-up
    char* ws = (char*)d_ws;
    size_t off = 0;
    __hip_bfloat16* qh   = (__hip_bfloat16*)(ws + off);  off += (size_t)R_TOT * 2048 * 2;      // 33,554,432
    __hip_bfloat16* ph   = (__hip_bfloat16*)(ws + off);  off += (size_t)R_TOT * 3 * 2048 * 2;  // 100,663,296
    __hip_bfloat16* h1m  = (__hip_bfloat16*)(ws + off);  off += (size_t)R_TOT * 256 * 2;       // 4,194,304
    __hip_bfloat16* h2m  = (__hip_bfloat16*)(ws + off);  off += (size_t)R_TOT * 256 * 2;       // 4,194,304
    __hip_bfloat16* wT1  = (__hip_bfloat16*)(ws + off);  off += 256 * 512 * 2;
    __hip_bfloat16* wT2  = (__hip_bfloat16*)(ws + off);  off += 256 * 256 * 2;
    __hip_bfloat16* wT3  = (__hip_bfloat16*)(ws + off);  off += 16 * 256 * 2;
    __hip_bfloat16* zT1  = (__hip_bfloat16*)(ws + off);  off += 256 * 2048 * 2;
    __hip_bfloat16* zT2  = (__hip_bfloat16*)(ws + off);  off += 256 * 256 * 2;
    __hip_bfloat16* zT3  = (__hip_bfloat16*)(ws + off);  off += 256 * 256 * 2;
    __hip_bfloat16* vT   = (__hip_bfloat16*)(ws + off);  off += 256 * 2048 * 2;

    float* qr = (float*)d_out;
    float* pr = (float*)d_out + QR_ELEMS;

    // 0) weight transpose + bf16 cast
    wtrans_kernel<<<dim3(16, 8), 256, 0, stream>>>(sw1, wT1, 512, 256);
    wtrans_kernel<<<dim3(8, 8),  256, 0, stream>>>(sw2, wT2, 256, 256);
    wtrans_kernel<<<dim3(8, 1),  256, 0, stream>>>(sw3, wT3, 256, 16);
    wtrans_kernel<<<dim3(64, 8), 256, 0, stream>>>(zw1, zT1, 2048, 256);
    wtrans_kernel<<<dim3(8, 8),  256, 0, stream>>>(zw2, zT2, 256, 256);
    wtrans_kernel<<<dim3(8, 8),  256, 0, stream>>>(zw3, zT3, 256, 256);
    wtrans_kernel<<<dim3(64, 8), 256, 0, stream>>>(zvw, vT, 2048, 256);

    // 1) fused sam MLP + softmax + pooling
    sampool_kernel<<<R_TOT / 4, 512, 0, stream>>>(q, p, amsk, wT1, sb1, wT2, sb2, wT3, sb3, qh, ph);
    // 2-4) zdm MLP (bf16 MFMA)
    mlp_mfma_kernel<2048, true,  true,  true ><<<R_TOT / 32, 256, 0, stream>>>(qh, zT1, zb1, h1m);
    mlp_mfma_kernel<256,  true,  true,  true ><<<R_TOT / 32, 256, 0, stream>>>(h1m, zT2, zb2, h2m);
    mlp_mfma_kernel<256,  true,  false, false><<<R_TOT / 32, 256, 0, stream>>>(h2m, zT3, zb3, qr);
    // 5) pr = ph @ zdm_vec_w (bf16 MFMA)
    mlp_mfma_kernel<2048, false, false, false><<<(R_TOT * 3) / 32, 256, 0, stream>>>(ph, vT, nullptr, pr);

    (void)in_sizes; (void)n_in; (void)out_size; (void)ws_size;
}

// Round 5
// 575.386 us; speedup vs baseline: 1.1111x; 1.1111x over previous
//
#include <hip/hip_runtime.h>
#include <hip/hip_bf16.h>

// Problem constants
#define R_TOT   8192
#define A14     14
#define A_TOT   (R_TOT * A14)     // 114688
#define QR_ELEMS (R_TOT * 256)    // 2097152

typedef __attribute__((ext_vector_type(8))) short bf16x8;
typedef __attribute__((ext_vector_type(4))) float f32x4;
typedef __attribute__((ext_vector_type(4))) short short4v;

#define MFMA16(a, b, c) __builtin_amdgcn_mfma_f32_16x16x32_bf16((a), (b), (c), 0, 0, 0)

static __device__ __forceinline__ float b2f(short s) {
    return __uint_as_float(((unsigned)(unsigned short)s) << 16);
}

// ---------------------------------------------------------------------------
// Weight transpose + bf16 cast:  w[K][N] fp32  ->  wT[N][K] bf16
// ---------------------------------------------------------------------------
__global__ __launch_bounds__(256) void wtrans_kernel(
    const float* __restrict__ w, __hip_bfloat16* __restrict__ wT, int K, int N)
{
    __shared__ float tile[32][33];
    const int kb = blockIdx.x * 32, nb = blockIdx.y * 32;
    const int tx = threadIdx.x & 31, ty = threadIdx.x >> 5;   // 32 x 8
    #pragma unroll
    for (int i = 0; i < 32; i += 8) {
        int k = kb + ty + i, n = nb + tx;
        tile[ty + i][tx] = (k < K && n < N) ? w[(size_t)k * N + n] : 0.f;
    }
    __syncthreads();
    #pragma unroll
    for (int i = 0; i < 32; i += 8) {
        int n = nb + ty + i, k = kb + tx;
        if (n < N && k < K) wT[(size_t)n * K + k] = __float2bfloat16(tile[tx][ty + i]);
    }
}

// ---------------------------------------------------------------------------
// Fused sam MLP + masked softmax + pooling.  Block = 2 residues = 28 atoms
// (pad M=32), 256 threads = 4 waves (each owns a 64-col N slice).
// Full z[32][512] staged bf16 up-front -> barrier-free L1 k-loop with
// register double-buffered weight fragments.  sa + aw alias the dead
// norm-half of the z buffer.  Pool phase: float4 jobs (res,stream,c-quad);
// q for pooling comes from LDS z (bf16), p re-read from global as float4.
// LDS: zl 33,280 B + h1l 16,896 B = 50,176 B -> 3 blocks/CU.
// ---------------------------------------------------------------------------
__global__ __launch_bounds__(256, 3) void sampool_kernel(
    const float* __restrict__ q, const float* __restrict__ p,
    const float* __restrict__ atom_mask,
    const __hip_bfloat16* __restrict__ wT1, const float* __restrict__ b1,
    const __hip_bfloat16* __restrict__ wT2, const float* __restrict__ b2,
    const __hip_bfloat16* __restrict__ wT3, const float* __restrict__ b3,
    __hip_bfloat16* __restrict__ qh, __hip_bfloat16* __restrict__ ph)
{
    __shared__ __align__(16) __hip_bfloat16 zl[32][520];    // 33,280 B
    __shared__ __align__(16) __hip_bfloat16 h1l[32][264];   // 16,896 B
    // aliases into the norm-half of zl (dead after L1):
    //   sa_row(m)  = 16 floats at row m, byte offset 512  (cols 256-287)
    //   aw_buf(j)  = 112 floats at row j (j<4), byte offset 576 (cols 288-511)
    char* const zbase = (char*)&zl[0][0];
    #define SA_ROW(m)  ((float*)(zbase + (size_t)(m) * 1040 + 512))
    #define AW_BUF(j)  ((float*)(zbase + (size_t)(j) * 1040 + 576))

    const int tid = threadIdx.x;
    const int r0  = blockIdx.x * 2;      // 2 residues
    const int a0  = r0 * A14;            // 28 real atom rows, pad to 32
    const int wv  = tid >> 6;
    const int l   = tid & 63;
    const int lr  = l & 15;
    const int lh  = l >> 4;
    const int nbase = wv * 64;

    // ---- stage full z[32][512] as bf16 (16 independent float4-iterations) ----
    #pragma unroll
    for (int it = 0; it < 16; ++it) {
        const int g  = tid + it * 256;       // 0..4095
        const int m  = g >> 7;               // 0..31
        const int c4 = (g & 127) * 4;        // 0..508
        const int ar = a0 + m;
        const size_t arow = (size_t)((ar < A_TOT) ? ar : (A_TOT - 1));
        __hip_bfloat16 t[4];
        if (c4 < 256) {
            const float4 v = *(const float4*)&q[arow * 256 + c4];
            t[0] = __float2bfloat16(v.x); t[1] = __float2bfloat16(v.y);
            t[2] = __float2bfloat16(v.z); t[3] = __float2bfloat16(v.w);
        } else {
            const int cc = c4 - 256;
            const float4 pa = *(const float4*)&p[arow * 768 + 0 * 256 + cc];
            const float4 pb = *(const float4*)&p[arow * 768 + 1 * 256 + cc];
            const float4 pc = *(const float4*)&p[arow * 768 + 2 * 256 + cc];
            t[0] = __float2bfloat16(sqrtf(pa.x*pa.x + pb.x*pb.x + pc.x*pc.x + 1e-6f));
            t[1] = __float2bfloat16(sqrtf(pa.y*pa.y + pb.y*pb.y + pc.y*pc.y + 1e-6f));
            t[2] = __float2bfloat16(sqrtf(pa.z*pa.z + pb.z*pb.z + pc.z*pc.z + 1e-6f));
            t[3] = __float2bfloat16(sqrtf(pa.w*pa.w + pb.w*pb.w + pc.w*pc.w + 1e-6f));
        }
        *(short4v*)&zl[m][c4] = *(const short4v*)t;
    }
    __syncthreads();

    // ---- Layer 1: K=512 -> N=256, leaky; barrier-free, B-frag dbuf ----
    {
        f32x4 acc[2][4] = {};
        const __hip_bfloat16* pB[4];
        #pragma unroll
        for (int nt = 0; nt < 4; ++nt)
            pB[nt] = wT1 + (size_t)(nbase + nt * 16 + lr) * 512 + lh * 8;
        bf16x8 bc[4];
        #pragma unroll
        for (int nt = 0; nt < 4; ++nt) bc[nt] = *(const bf16x8*)(pB[nt]);
        #pragma unroll
        for (int k0 = 0; k0 < 512; k0 += 32) {
            bf16x8 bn[4];
            if (k0 + 32 < 512) {
                #pragma unroll
                for (int nt = 0; nt < 4; ++nt)
                    bn[nt] = *(const bf16x8*)(pB[nt] + k0 + 32);
            }
            const int kc = k0 + lh * 8;
            const bf16x8 a0f = *(const bf16x8*)&zl[lr][kc];
            const bf16x8 a1f = *(const bf16x8*)&zl[16 + lr][kc];
            #pragma unroll
            for (int nt = 0; nt < 4; ++nt) {
                acc[0][nt] = MFMA16(a0f, bc[nt], acc[0][nt]);
                acc[1][nt] = MFMA16(a1f, bc[nt], acc[1][nt]);
            }
            #pragma unroll
            for (int nt = 0; nt < 4; ++nt) bc[nt] = bn[nt];
        }
        #pragma unroll
        for (int nt = 0; nt < 4; ++nt) {
            const int n = nbase + nt * 16 + lr;
            const float bv = b1[n];
            #pragma unroll
            for (int mt = 0; mt < 2; ++mt)
                #pragma unroll
                for (int v = 0; v < 4; ++v) {
                    float x = acc[mt][nt][v] + bv;
                    x = x >= 0.f ? x : 0.01f * x;
                    h1l[mt * 16 + lh * 4 + v][n] = __float2bfloat16(x);
                }
        }
    }
    __syncthreads();

    // ---- Layer 2: K=256 -> N=256, leaky; B-frag dbuf ----
    {
        f32x4 acc[2][4] = {};
        const __hip_bfloat16* pB[4];
        #pragma unroll
        for (int nt = 0; nt < 4; ++nt)
            pB[nt] = wT2 + (size_t)(nbase + nt * 16 + lr) * 256 + lh * 8;
        bf16x8 bc[4];
        #pragma unroll
        for (int nt = 0; nt < 4; ++nt) bc[nt] = *(const bf16x8*)(pB[nt]);
        #pragma unroll
        for (int k0 = 0; k0 < 256; k0 += 32) {
            bf16x8 bn[4];
            if (k0 + 32 < 256) {
                #pragma unroll
                for (int nt = 0; nt < 4; ++nt)
                    bn[nt] = *(const bf16x8*)(pB[nt] + k0 + 32);
            }
            const int kc = k0 + lh * 8;
            const bf16x8 a0f = *(const bf16x8*)&h1l[lr][kc];
            const bf16x8 a1f = *(const bf16x8*)&h1l[16 + lr][kc];
            #pragma unroll
            for (int nt = 0; nt < 4; ++nt) {
                acc[0][nt] = MFMA16(a0f, bc[nt], acc[0][nt]);
                acc[1][nt] = MFMA16(a1f, bc[nt], acc[1][nt]);
            }
            #pragma unroll
            for (int nt = 0; nt < 4; ++nt) bc[nt] = bn[nt];
        }
        __syncthreads();   // everyone done READING h1 before h2 overwrite
        #pragma unroll
        for (int nt = 0; nt < 4; ++nt) {
            const int n = nbase + nt * 16 + lr;
            const float bv = b2[n];
            #pragma unroll
            for (int mt = 0; mt < 2; ++mt)
                #pragma unroll
                for (int v = 0; v < 4; ++v) {
                    float x = acc[mt][nt][v] + bv;
                    x = x >= 0.f ? x : 0.01f * x;
                    h1l[mt * 16 + lh * 4 + v][n] = __float2bfloat16(x);   // h2
                }
        }
    }
    __syncthreads();

    // ---- Layer 3: K=256 -> 16 cols; waves 0,1 own m-frags 0,1 ----
    if (wv < 2) {
        f32x4 a3 = {};
        const __hip_bfloat16* pW3 = wT3 + (size_t)lr * 256 + lh * 8;
        bf16x8 bwc = *(const bf16x8*)(pW3);
        #pragma unroll
        for (int k0 = 0; k0 < 256; k0 += 32) {
            bf16x8 bwn;
            if (k0 + 32 < 256) bwn = *(const bf16x8*)(pW3 + k0 + 32);
            const int kc = k0 + lh * 8;
            const bf16x8 af = *(const bf16x8*)&h1l[wv * 16 + lr][kc];
            a3 = MFMA16(af, bwc, a3);
            bwc = bwn;
        }
        const float bv = b3[lr];
        #pragma unroll
        for (int v = 0; v < 4; ++v)
            SA_ROW(wv * 16 + lh * 4 + v)[lr] = a3[v] + bv;
    }
    __syncthreads();

    // ---- masked softmax: 2 residues x 16 channels = 32 threads ----
    if (tid < 32) {
        const int res = tid >> 4, ch = tid & 15;
        const size_t rg = (size_t)(r0 + res);
        float sl[14];
        float mx = -3.0e38f, anym = 0.f;
        #pragma unroll
        for (int a = 0; a < 14; ++a) {
            const float m = atom_mask[rg * 14 + a];
            anym = fmaxf(anym, m);
            const float lm = (1.0f - m + 1e-6f) / (m - 1e-6f);
            const float v = SA_ROW(res * 14 + a)[ch] + lm;
            sl[a] = v;
            mx = fmaxf(mx, v);
        }
        float s = 0.f;
        #pragma unroll
        for (int a = 0; a < 14; ++a) { sl[a] = expf(sl[a] - mx); s += sl[a]; }
        const float inv = ((anym != 0.f) ? 1.f : 0.f) / s;   // fold residue mask
        float* const aw = AW_BUF((ch & 1) * 2 + res);
        const int h = ch >> 1;
        #pragma unroll
        for (int a = 0; a < 14; ++a)
            aw[a * 8 + h] = sl[a] * inv;
    }
    __syncthreads();

    // ---- pooling: 512 jobs = 2 res x {q,px0,px1,px2} x 64 c-quads ----
    #pragma unroll
    for (int jr = 0; jr < 2; ++jr) {
        const int job = tid + jr * 256;
        const int res = job >> 8;
        const int s   = (job >> 6) & 3;      // 0:q  1..3:p[x]
        const int c4  = (job & 63) * 4;
        const size_t rg = (size_t)(r0 + res);
        const float* const aw = AW_BUF(((s == 0) ? 0 : 1) * 2 + res);
        float acc4[4][8] = {};
        if (s == 0) {
            #pragma unroll
            for (int a = 0; a < 14; ++a) {
                const short4v qv = *(const short4v*)&zl[res * 14 + a][c4];
                const float qf[4] = { b2f(qv.x), b2f(qv.y), b2f(qv.z), b2f(qv.w) };
                #pragma unroll
                for (int ci = 0; ci < 4; ++ci)
                    #pragma unroll
                    for (int h = 0; h < 8; ++h)
                        acc4[ci][h] = fmaf(qf[ci], aw[a * 8 + h], acc4[ci][h]);
            }
        } else {
            const int x = s - 1;
            #pragma unroll
            for (int a = 0; a < 14; ++a) {
                const float4 pv = *(const float4*)&p[(rg * 14 + a) * 768 + (size_t)x * 256 + c4];
                const float pf[4] = { pv.x, pv.y, pv.z, pv.w };
                #pragma unroll
                for (int ci = 0; ci < 4; ++ci)
                    #pragma unroll
                    for (int h = 0; h < 8; ++h)
                        acc4[ci][h] = fmaf(pf[ci], aw[a * 8 + h], acc4[ci][h]);
            }
        }
        alignas(16) __hip_bfloat16 tmp[32];
        #pragma unroll
        for (int ci = 0; ci < 4; ++ci)
            #pragma unroll
            for (int h = 0; h < 8; ++h)
                tmp[ci * 8 + h] = __float2bfloat16(acc4[ci][h]);
        __hip_bfloat16* const dst = (s == 0)
            ? &qh[rg * 2048 + (size_t)c4 * 8]
            : &ph[(rg * 3 + (s - 1)) * 2048 + (size_t)c4 * 8];
        #pragma unroll
        for (int u = 0; u < 4; ++u)
            *reinterpret_cast<int4*>(dst + u * 8) = *reinterpret_cast<const int4*>(tmp + u * 8);
    }
    #undef SA_ROW
    #undef AW_BUF
}

// ---------------------------------------------------------------------------
// Fused zdm MLP: qh[8192][2048] -> 256 -> 256 -> 256 (qr fp32).
// Block = 32 rows, 256 threads = 4 waves.  K=2048 staged in 8 chunks of 256
// with single-barrier double-buffered LDS + early-issued global loads.
// ---------------------------------------------------------------------------
__global__ __launch_bounds__(256, 3) void zdm_kernel(
    const __hip_bfloat16* __restrict__ x, const __hip_bfloat16* __restrict__ zT1,
    const float* __restrict__ zb1, const __hip_bfloat16* __restrict__ zT2,
    const float* __restrict__ zb2, const __hip_bfloat16* __restrict__ zT3,
    const float* __restrict__ zb3, float* __restrict__ qr)
{
    __shared__ __align__(16) __hip_bfloat16 xl[2][32][264];  // 33,792 B
    __shared__ __align__(16) __hip_bfloat16 hl[32][264];     // 16,896 B

    const int tid = threadIdx.x;
    const int a0  = blockIdx.x * 32;
    const int wv  = tid >> 6;
    const int l   = tid & 63;
    const int lr  = l & 15;
    const int lh  = l >> 4;
    const int nbase = wv * 64;

    const int sm = (tid + 0 * 256) >> 5 ;  (void)sm;
    // staging geometry: 1024 int4 units per chunk; 4 per thread
    int4 st[4];
    #define LOADC(c)                                                          \
        { _Pragma("unroll")                                                   \
          for (int it = 0; it < 4; ++it) {                                    \
              const int g = tid + it * 256;                                   \
              const int m = g >> 5, c8 = (g & 31) * 8;                        \
              st[it] = *(const int4*)&x[(size_t)(a0 + m) * 2048 + (c) * 256 + c8]; } }
    #define WRITEC(buf)                                                       \
        { _Pragma("unroll")                                                   \
          for (int it = 0; it < 4; ++it) {                                    \
              const int g = tid + it * 256;                                   \
              const int m = g >> 5, c8 = (g & 31) * 8;                        \
              *(int4*)&xl[buf][m][c8] = st[it]; } }

    // ---- Layer 1: K=2048 ----
    f32x4 acc[2][4] = {};
    {
        const __hip_bfloat16* pB[4];
        #pragma unroll
        for (int nt = 0; nt < 4; ++nt)
            pB[nt] = zT1 + (size_t)(nbase + nt * 16 + lr) * 2048 + lh * 8;

        LOADC(0); WRITEC(0); __syncthreads();
        for (int c = 0; c < 8; ++c) {
            if (c < 7) LOADC(c + 1);            // issue next chunk early
            const __hip_bfloat16 (* const cur)[264] = xl[c & 1];
            bf16x8 bc[4];
            #pragma unroll
            for (int nt = 0; nt < 4; ++nt) bc[nt] = *(const bf16x8*)(pB[nt] + c * 256);
            #pragma unroll
            for (int k0 = 0; k0 < 256; k0 += 32) {
                bf16x8 bn[4];
                if (k0 + 32 < 256) {
                    #pragma unroll
                    for (int nt = 0; nt < 4; ++nt)
                        bn[nt] = *(const bf16x8*)(pB[nt] + c * 256 + k0 + 32);
                }
                const int kc = k0 + lh * 8;
                const bf16x8 a0f = *(const bf16x8*)&cur[lr][kc];
                const bf16x8 a1f = *(const bf16x8*)&cur[16 + lr][kc];
                #pragma unroll
                for (int nt = 0; nt < 4; ++nt) {
                    acc[0][nt] = MFMA16(a0f, bc[nt], acc[0][nt]);
                    acc[1][nt] = MFMA16(a1f, bc[nt], acc[1][nt]);
                }
                #pragma unroll
                for (int nt = 0; nt < 4; ++nt) bc[nt] = bn[nt];
            }
            if (c < 7) WRITEC((c + 1) & 1);
            __syncthreads();
        }
        #pragma unroll
        for (int nt = 0; nt < 4; ++nt) {
            const int n = nbase + nt * 16 + lr;
            const float bv = zb1[n];
            #pragma unroll
            for (int mt = 0; mt < 2; ++mt)
                #pragma unroll
                for (int v = 0; v < 4; ++v) {
                    float xv = acc[mt][nt][v] + bv;
                    xv = xv >= 0.f ? xv : 0.01f * xv;
                    hl[mt * 16 + lh * 4 + v][n] = __float2bfloat16(xv);
                }
        }
    }
    __syncthreads();

    // ---- Layer 2: K=256, leaky, write back into hl ----
    {
        f32x4 acc2[2][4] = {};
        const __hip_bfloat16* pB[4];
        #pragma unroll
        for (int nt = 0; nt < 4; ++nt)
            pB[nt] = zT2 + (size_t)(nbase + nt * 16 + lr) * 256 + lh * 8;
        bf16x8 bc[4];
        #pragma unroll
        for (int nt = 0; nt < 4; ++nt) bc[nt] = *(const bf16x8*)(pB[nt]);
        #pragma unroll
        for (int k0 = 0; k0 < 256; k0 += 32) {
            bf16x8 bn[4];
            if (k0 + 32 < 256) {
                #pragma unroll
                for (int nt = 0; nt < 4; ++nt)
                    bn[nt] = *(const bf16x8*)(pB[nt] + k0 + 32);
            }
            const int kc = k0 + lh * 8;
            const bf16x8 a0f = *(const bf16x8*)&hl[lr][kc];
            const bf16x8 a1f = *(const bf16x8*)&hl[16 + lr][kc];
            #pragma unroll
            for (int nt = 0; nt < 4; ++nt) {
                acc2[0][nt] = MFMA16(a0f, bc[nt], acc2[0][nt]);
                acc2[1][nt] = MFMA16(a1f, bc[nt], acc2[1][nt]);
            }
            #pragma unroll
            for (int nt = 0; nt < 4; ++nt) bc[nt] = bn[nt];
        }
        __syncthreads();
        #pragma unroll
        for (int nt = 0; nt < 4; ++nt) {
            const int n = nbase + nt * 16 + lr;
            const float bv = zb2[n];
            #pragma unroll
            for (int mt = 0; mt < 2; ++mt)
                #pragma unroll
                for (int v = 0; v < 4; ++v) {
                    float xv = acc2[mt][nt][v] + bv;
                    xv = xv >= 0.f ? xv : 0.01f * xv;
                    hl[mt * 16 + lh * 4 + v][n] = __float2bfloat16(xv);
                }
        }
    }
    __syncthreads();

    // ---- Layer 3: K=256 -> qr (fp32, bias, no act) ----
    {
        f32x4 acc3[2][4] = {};
        const __hip_bfloat16* pB[4];
        #pragma unroll
        for (int nt = 0; nt < 4; ++nt)
            pB[nt] = zT3 + (size_t)(nbase + nt * 16 + lr) * 256 + lh * 8;
        bf16x8 bc[4];
        #pragma unroll
        for (int nt = 0; nt < 4; ++nt) bc[nt] = *(const bf16x8*)(pB[nt]);
        #pragma unroll
        for (int k0 = 0; k0 < 256; k0 += 32) {
            bf16x8 bn[4];
            if (k0 + 32 < 256) {
                #pragma unroll
                for (int nt = 0; nt < 4; ++nt)
                    bn[nt] = *(const bf16x8*)(pB[nt] + k0 + 32);
            }
            const int kc = k0 + lh * 8;
            const bf16x8 a0f = *(const bf16x8*)&hl[lr][kc];
            const bf16x8 a1f = *(const bf16x8*)&hl[16 + lr][kc];
            #pragma unroll
            for (int nt = 0; nt < 4; ++nt) {
                acc3[0][nt] = MFMA16(a0f, bc[nt], acc3[0][nt]);
                acc3[1][nt] = MFMA16(a1f, bc[nt], acc3[1][nt]);
            }
            #pragma unroll
            for (int nt = 0; nt < 4; ++nt) bc[nt] = bn[nt];
        }
        #pragma unroll
        for (int nt = 0; nt < 4; ++nt) {
            const int n = nbase + nt * 16 + lr;
            const float bv = zb3[n];
            #pragma unroll
            for (int mt = 0; mt < 2; ++mt)
                #pragma unroll
                for (int v = 0; v < 4; ++v)
                    qr[(size_t)(a0 + mt * 16 + lh * 4 + v) * 256 + n] = acc3[mt][nt][v] + bv;
        }
    }
    #undef LOADC
    #undef WRITEC
}

// ---------------------------------------------------------------------------
// pr = ph[24576][2048] @ vT  (fp32 out, no bias/act).  Same dbuf structure.
// ---------------------------------------------------------------------------
__global__ __launch_bounds__(256, 3) void pr_kernel(
    const __hip_bfloat16* __restrict__ x, const __hip_bfloat16* __restrict__ vT,
    float* __restrict__ out)
{
    __shared__ __align__(16) __hip_bfloat16 xl[2][32][264];  // 33,792 B

    const int tid = threadIdx.x;
    const int a0  = blockIdx.x * 32;
    const int wv  = tid >> 6;
    const int l   = tid & 63;
    const int lr  = l & 15;
    const int lh  = l >> 4;
    const int nbase = wv * 64;

    int4 st[4];
    #define LOADC(c)                                                          \
        { _Pragma("unroll")                                                   \
          for (int it = 0; it < 4; ++it) {                                    \
              const int g = tid + it * 256;                                   \
              const int m = g >> 5, c8 = (g & 31) * 8;                        \
              st[it] = *(const int4*)&x[(size_t)(a0 + m) * 2048 + (c) * 256 + c8]; } }
    #define WRITEC(buf)                                                       \
        { _Pragma("unroll")                                                   \
          for (int it = 0; it < 4; ++it) {                                    \
              const int g = tid + it * 256;                                   \
              const int m = g >> 5, c8 = (g & 31) * 8;                        \
              *(int4*)&xl[buf][m][c8] = st[it]; } }

    f32x4 acc[2][4] = {};
    const __hip_bfloat16* pB[4];
    #pragma unroll
    for (int nt = 0; nt < 4; ++nt)
        pB[nt] = vT + (size_t)(nbase + nt * 16 + lr) * 2048 + lh * 8;

    LOADC(0); WRITEC(0); __syncthreads();
    for (int c = 0; c < 8; ++c) {
        if (c < 7) LOADC(c + 1);
        const __hip_bfloat16 (* const cur)[264] = xl[c & 1];
        bf16x8 bc[4];
        #pragma unroll
        for (int nt = 0; nt < 4; ++nt) bc[nt] = *(const bf16x8*)(pB[nt] + c * 256);
        #pragma unroll
        for (int k0 = 0; k0 < 256; k0 += 32) {
            bf16x8 bn[4];
            if (k0 + 32 < 256) {
                #pragma unroll
                for (int nt = 0; nt < 4; ++nt)
                    bn[nt] = *(const bf16x8*)(pB[nt] + c * 256 + k0 + 32);
            }
            const int kc = k0 + lh * 8;
            const bf16x8 a0f = *(const bf16x8*)&cur[lr][kc];
            const bf16x8 a1f = *(const bf16x8*)&cur[16 + lr][kc];
            #pragma unroll
            for (int nt = 0; nt < 4; ++nt) {
                acc[0][nt] = MFMA16(a0f, bc[nt], acc[0][nt]);
                acc[1][nt] = MFMA16(a1f, bc[nt], acc[1][nt]);
            }
            #pragma unroll
            for (int nt = 0; nt < 4; ++nt) bc[nt] = bn[nt];
        }
        if (c < 7) WRITEC((c + 1) & 1);
        __syncthreads();
    }
    #pragma unroll
    for (int nt = 0; nt < 4; ++nt) {
        const int n = nbase + nt * 16 + lr;
        #pragma unroll
        for (int mt = 0; mt < 2; ++mt)
            #pragma unroll
            for (int v = 0; v < 4; ++v)
                out[(size_t)(a0 + mt * 16 + lh * 4 + v) * 256 + n] = acc[mt][nt][v];
    }
    #undef LOADC
    #undef WRITEC
}

// ---------------------------------------------------------------------------
extern "C" void kernel_launch(void* const* d_in, const int* in_sizes, int n_in,
                              void* d_out, int out_size, void* d_ws, size_t ws_size,
                              hipStream_t stream)
{
    const float* q    = (const float*)d_in[0];
    const float* p    = (const float*)d_in[1];
    const float* amsk = (const float*)d_in[2];
    const float* sw1  = (const float*)d_in[3];
    const float* sb1  = (const float*)d_in[4];
    const float* sw2  = (const float*)d_in[5];
    const float* sb2  = (const float*)d_in[6];
    const float* sw3  = (const float*)d_in[7];
    const float* sb3  = (const float*)d_in[8];
    const float* zw1  = (const float*)d_in[9];
    const float* zb1  = (const float*)d_in[10];
    const float* zw2  = (const float*)d_in[11];
    const float* zb2  = (const float*)d_in[12];
    const float* zw3  = (const float*)d_in[13];
    const float* zb3  = (const float*)d_in[14];
    const float* zvw  = (const float*)d_in[15];

    // workspace carve-up
    char* ws = (char*)d_ws;
    size_t off = 0;
    __hip_bfloat16* qh   = (__hip_bfloat16*)(ws + off);  off += (size_t)R_TOT * 2048 * 2;      // 33,554,432
    __hip_bfloat16* ph   = (__hip_bfloat16*)(ws + off);  off += (size_t)R_TOT * 3 * 2048 * 2;  // 100,663,296
    __hip_bfloat16* wT1  = (__hip_bfloat16*)(ws + off);  off += 256 * 512 * 2;
    __hip_bfloat16* wT2  = (__hip_bfloat16*)(ws + off);  off += 256 * 256 * 2;
    __hip_bfloat16* wT3  = (__hip_bfloat16*)(ws + off);  off += 16 * 256 * 2;
    __hip_bfloat16* zT1  = (__hip_bfloat16*)(ws + off);  off += 256 * 2048 * 2;
    __hip_bfloat16* zT2  = (__hip_bfloat16*)(ws + off);  off += 256 * 256 * 2;
    __hip_bfloat16* zT3  = (__hip_bfloat16*)(ws + off);  off += 256 * 256 * 2;
    __hip_bfloat16* vT   = (__hip_bfloat16*)(ws + off);  off += 256 * 2048 * 2;

    float* qr = (float*)d_out;
    float* pr = (float*)d_out + QR_ELEMS;

    // 0) weight transpose + bf16 cast
    wtrans_kernel<<<dim3(16, 8), 256, 0, stream>>>(sw1, wT1, 512, 256);
    wtrans_kernel<<<dim3(8, 8),  256, 0, stream>>>(sw2, wT2, 256, 256);
    wtrans_kernel<<<dim3(8, 1),  256, 0, stream>>>(sw3, wT3, 256, 16);
    wtrans_kernel<<<dim3(64, 8), 256, 0, stream>>>(zw1, zT1, 2048, 256);
    wtrans_kernel<<<dim3(8, 8),  256, 0, stream>>>(zw2, zT2, 256, 256);
    wtrans_kernel<<<dim3(8, 8),  256, 0, stream>>>(zw3, zT3, 256, 256);
    wtrans_kernel<<<dim3(64, 8), 256, 0, stream>>>(zvw, vT, 2048, 256);

    // 1) fused sam MLP + softmax + pooling  (2 residues / block)
    sampool_kernel<<<R_TOT / 2, 256, 0, stream>>>(q, p, amsk, wT1, sb1, wT2, sb2, wT3, sb3, qh, ph);
    // 2) fused zdm MLP -> qr
    zdm_kernel<<<R_TOT / 32, 256, 0, stream>>>(qh, zT1, zb1, zT2, zb2, zT3, zb3, qr);
    // 3) pr = ph @ zdm_vec_w
    pr_kernel<<<(R_TOT * 3) / 32, 256, 0, stream>>>(ph, vT, pr);

    (void)in_sizes; (void)n_in; (void)out_size; (void)ws_size;
}